// Round 1
// baseline (331.451 us; speedup 1.0000x reference)
//
#include <hip/hip_runtime.h>
#include <cstdint>
#include <cstddef>

#define B_   32
#define TIN  512
#define D_   384
#define F_   384
#define TOUT 4096
#define TPAD 514            // 512 + zero row on each side
#define MTOT (B_ * TIN)     // 16384

typedef __bf16 bf16x8 __attribute__((ext_vector_type(8)));
typedef float  f32x4  __attribute__((ext_vector_type(4)));

__device__ __forceinline__ unsigned short f2bf(float f) {
  unsigned int u = __float_as_uint(f);
  u += 0x7fff + ((u >> 16) & 1);   // round-to-nearest-even
  return (unsigned short)(u >> 16);
}

__device__ __forceinline__ void load16_to_lds(const void* g, void* l) {
  __builtin_amdgcn_global_load_lds(
      (const __attribute__((address_space(1))) unsigned int*)g,
      (__attribute__((address_space(3))) unsigned int*)l, 16, 0, 0);
}

// ---------------------------------------------------------------- prep
// Wt[k][f][d] = w[f][d][k] as bf16 (B^T layout for the GEMM), plus zero the
// two pad rows of h1p per batch (ws is poisoned 0xAA before every call).
__global__ void prep_weights(const float* __restrict__ w1, const float* __restrict__ w2,
                             unsigned short* __restrict__ Wt1, unsigned short* __restrict__ Wt2,
                             unsigned short* __restrict__ h1p) {
  int g = blockIdx.x * 256 + threadIdx.x;
  const int WE = 3 * F_ * D_;                 // 442368
  if (g < 2 * WE) {
    int which = g >= WE;
    const float* w = which ? w2 : w1;
    unsigned short* o = which ? Wt2 : Wt1;
    int e = g - which * WE;
    int k = e / (F_ * D_);
    int rem = e - k * (F_ * D_);
    int f = rem / D_;
    int d = rem - f * D_;
    o[e] = f2bf(w[(f * D_ + d) * 3 + k]);
  } else {
    int z = g - 2 * WE;                       // < 24576
    int zr = z / D_;
    int c = z - zr * D_;
    int b = zr >> 1;
    int tp = (zr & 1) ? (TPAD - 1) : 0;
    h1p[((size_t)(b * TPAD + tp)) * D_ + c] = 0;
  }
}

// xp[b][tp][d]: tp==0 / tp==513 are zeros, else bf16(x[b][tp-1][d])
__global__ void pad_x(const float4* __restrict__ x4, unsigned short* __restrict__ xp) {
  int g = blockIdx.x * 256 + threadIdx.x;     // 32*514*96 = 1,579,008
  int row = g / 96;
  int c4 = g - row * 96;
  int b = row / TPAD;
  int tp = row - b * TPAD;
  ushort4 o;
  if (tp == 0 || tp == TPAD - 1) {
    o.x = 0; o.y = 0; o.z = 0; o.w = 0;
  } else {
    float4 v = x4[((size_t)(b * TIN + tp - 1)) * 96 + c4];
    o.x = f2bf(v.x); o.y = f2bf(v.y); o.z = f2bf(v.z); o.w = f2bf(v.w);
  }
  *(ushort4*)(xp + (size_t)row * D_ + c4 * 4) = o;
}

// ---------------------------------------------------------------- conv GEMM
// out[bt][f] = sum_{kw,d} Ap[b][t+kw][d] * Wt[kw][f][d] + bias[f]
// 128x128 tile, BK=32, 4 waves x (4x4) mfma_f32_16x16x32_bf16, m97 staging.
__global__ __launch_bounds__(256) void conv_gemm(const unsigned short* __restrict__ Ap,
                                                 const unsigned short* __restrict__ Wt,
                                                 const float* __restrict__ bias,
                                                 float* __restrict__ out) {
  __shared__ __align__(16) unsigned short As[128 * 32];
  __shared__ __align__(16) unsigned short Bs[128 * 32];
  const int tid  = threadIdx.x;
  const int wave = tid >> 6;
  const int lane = tid & 63;
  const int quad = lane >> 4;
  const int l15  = lane & 15;
  const int wm = (wave >> 1) * 64;
  const int wn = (wave & 1) * 64;
  const int m0 = blockIdx.x * 128;
  const int n0 = blockIdx.y * 128;
  const int b  = m0 >> 9;          // M-tiles never cross batch (512 % 128 == 0)
  const int t0 = m0 & 511;

  const int srow = tid >> 2;       // 0..63
  const int scol = (tid & 3) * 8;  // 0,8,16,24

  f32x4 acc[4][4];
  for (int i = 0; i < 4; ++i)
    for (int j = 0; j < 4; ++j)
      acc[i][j] = (f32x4){0.f, 0.f, 0.f, 0.f};

  for (int kc = 0; kc < 36; ++kc) {
    int kw = kc / 12;
    int d0 = (kc - kw * 12) * 32;
    for (int r = 0; r < 2; ++r) {
      int row = r * 64 + srow;
      const unsigned short* ga = Ap + (size_t)(b * TPAD + t0 + row + kw) * D_ + d0 + scol;
      load16_to_lds(ga, (char*)As + r * 4096 + wave * 1024);
      const unsigned short* gb = Wt + (size_t)(kw * F_ + n0 + row) * D_ + d0 + scol;
      load16_to_lds(gb, (char*)Bs + r * 4096 + wave * 1024);
    }
    __syncthreads();   // barrier drains vmcnt -> LDS tiles visible
    bf16x8 av[4], bv[4];
    for (int mi = 0; mi < 4; ++mi)
      av[mi] = *(const bf16x8*)(As + (wm + mi * 16 + l15) * 32 + quad * 8);
    for (int ni = 0; ni < 4; ++ni)
      bv[ni] = *(const bf16x8*)(Bs + (wn + ni * 16 + l15) * 32 + quad * 8);
    for (int mi = 0; mi < 4; ++mi)
      for (int ni = 0; ni < 4; ++ni)
        acc[mi][ni] = __builtin_amdgcn_mfma_f32_16x16x32_bf16(av[mi], bv[ni], acc[mi][ni], 0, 0, 0);
    __syncthreads();   // protect LDS from next iteration's staging
  }

  for (int mi = 0; mi < 4; ++mi) {
    int mrow = m0 + wm + mi * 16 + quad * 4;
    for (int ni = 0; ni < 4; ++ni) {
      int ncol = n0 + wn + ni * 16 + l15;
      float bb = bias[ncol];
      for (int r = 0; r < 4; ++r)
        out[(size_t)(mrow + r) * F_ + ncol] = acc[mi][ni][r] + bb;
    }
  }
}

// ---------------------------------------------------------------- LN passes
// one wave per row (384 cols = 6 per lane)
__global__ void ln_relu(const float* __restrict__ in, const float* __restrict__ gam,
                        const float* __restrict__ bet, unsigned short* __restrict__ hp) {
  int row = blockIdx.x * 4 + (threadIdx.x >> 6);
  int lane = threadIdx.x & 63;
  const float* p = in + (size_t)row * F_;
  float v[6];
  float s = 0.f, ss = 0.f;
  for (int j = 0; j < 6; ++j) {
    v[j] = p[lane + j * 64];
    s += v[j];
    ss += v[j] * v[j];
  }
  for (int off = 32; off; off >>= 1) {
    s  += __shfl_xor(s, off);
    ss += __shfl_xor(ss, off);
  }
  float mean = s * (1.f / 384.f);
  float var  = ss * (1.f / 384.f) - mean * mean;
  float rstd = rsqrtf(var + 1e-5f);
  int b = row >> 9, t = row & 511;
  unsigned short* o = hp + ((size_t)(b * TPAD + t + 1)) * D_;
  for (int j = 0; j < 6; ++j) {
    int c = lane + j * 64;
    float y = (v[j] - mean) * rstd * gam[c] + bet[c];
    y = y > 0.f ? y : 0.f;
    o[c] = f2bf(y);
  }
}

__global__ void ln_dot(const float* __restrict__ in, const float* __restrict__ gam,
                       const float* __restrict__ bet, const float* __restrict__ lw,
                       const float* __restrict__ lb, float* __restrict__ dur) {
  int row = blockIdx.x * 4 + (threadIdx.x >> 6);
  int lane = threadIdx.x & 63;
  const float* p = in + (size_t)row * F_;
  float v[6];
  float s = 0.f, ss = 0.f;
  for (int j = 0; j < 6; ++j) {
    v[j] = p[lane + j * 64];
    s += v[j];
    ss += v[j] * v[j];
  }
  for (int off = 32; off; off >>= 1) {
    s  += __shfl_xor(s, off);
    ss += __shfl_xor(ss, off);
  }
  float mean = s * (1.f / 384.f);
  float var  = ss * (1.f / 384.f) - mean * mean;
  float rstd = rsqrtf(var + 1e-5f);
  float acc = 0.f;
  for (int j = 0; j < 6; ++j) {
    int c = lane + j * 64;
    float y = (v[j] - mean) * rstd * gam[c] + bet[c];
    y = y > 0.f ? y : 0.f;
    acc += y * lw[c];
  }
  for (int off = 32; off; off >>= 1) acc += __shfl_xor(acc, off);
  if (lane == 0) dur[row] = acc + lb[0];
}

// ---------------------------------------------------------------- regulate
__global__ void cumsum_idx(const int* __restrict__ target, int* __restrict__ idxv) {
  __shared__ int ends[512];
  int t = threadIdx.x, b = blockIdx.x;
  ends[t] = target[b * TIN + t];
  __syncthreads();
  for (int off = 1; off < 512; off <<= 1) {
    int add = (t >= off) ? ends[t - off] : 0;
    __syncthreads();
    ends[t] += add;
    __syncthreads();
  }
  for (int p = 0; p < 8; ++p) {
    int m = p * 512 + t;
    int lo = 0, hi = 512;              // first j with ends[j] > m
    while (lo < hi) {
      int mid = (lo + hi) >> 1;
      if (ends[mid] <= m) lo = mid + 1; else hi = mid;
    }
    idxv[b * TOUT + m] = (lo < TIN) ? lo : -1;
  }
}

__global__ void gather(const float4* __restrict__ x4, const int* __restrict__ idxv,
                       float4* __restrict__ out4) {
  int g = blockIdx.x * 256 + threadIdx.x;   // 12,582,912 float4s
  int fr = g / 96;
  int c = g - fr * 96;
  int id = idxv[fr];
  int b = fr >> 12;
  float4 v = {0.f, 0.f, 0.f, 0.f};
  if (id >= 0) v = x4[(size_t)(b * TIN + id) * 96 + c];
  out4[g] = v;
}

// ---------------------------------------------------------------- launch
extern "C" void kernel_launch(void* const* d_in, const int* in_sizes, int n_in,
                              void* d_out, int out_size, void* d_ws, size_t ws_size,
                              hipStream_t stream) {
  const float* x      = (const float*)d_in[0];
  const int*   target = (const int*)d_in[1];
  const float* w1  = (const float*)d_in[3];
  const float* b1  = (const float*)d_in[4];
  const float* g1  = (const float*)d_in[5];
  const float* be1 = (const float*)d_in[6];
  const float* w2  = (const float*)d_in[7];
  const float* b2  = (const float*)d_in[8];
  const float* g2  = (const float*)d_in[9];
  const float* be2 = (const float*)d_in[10];
  const float* lw  = (const float*)d_in[11];
  const float* lb  = (const float*)d_in[12];

  float* out = (float*)d_out;
  float* dur = out + (size_t)B_ * TOUT * D_;   // outputs concatenated flat

  // workspace carve (all offsets 256B-aligned)
  char* ws = (char*)d_ws;
  unsigned short* xp  = (unsigned short*)(ws);                 // 32*514*384 bf16 = 12,632,064 B
  unsigned short* h1p = (unsigned short*)(ws + 12632064);      // same
  unsigned short* Wt1 = (unsigned short*)(ws + 25264128);      // 3*384*384 bf16 = 884,736 B
  unsigned short* Wt2 = (unsigned short*)(ws + 26148864);      // 884,736 B
  float*          gbf = (float*)(ws + 27033600);               // 16384*384 f32 = 25,165,824 B
  int*            idxv = (int*)(ws + 52199424);                // 32*4096 int = 524,288 B

  hipLaunchKernelGGL(prep_weights, dim3(3552), dim3(256), 0, stream, w1, w2, Wt1, Wt2, h1p);
  hipLaunchKernelGGL(pad_x, dim3(6168), dim3(256), 0, stream, (const float4*)x, xp);
  hipLaunchKernelGGL(conv_gemm, dim3(128, 3), dim3(256), 0, stream, xp, Wt1, b1, gbf);
  hipLaunchKernelGGL(ln_relu, dim3(4096), dim3(256), 0, stream, gbf, g1, be1, h1p);
  hipLaunchKernelGGL(conv_gemm, dim3(128, 3), dim3(256), 0, stream, h1p, Wt2, b2, gbf);
  hipLaunchKernelGGL(ln_dot, dim3(4096), dim3(256), 0, stream, gbf, g2, be2, lw, lb, dur);
  hipLaunchKernelGGL(cumsum_idx, dim3(32), dim3(512), 0, stream, target, idxv);
  hipLaunchKernelGGL(gather, dim3(49152), dim3(256), 0, stream, (const float4*)x, idxv, (float4*)out);
}

// Round 2
// 321.688 us; speedup vs baseline: 1.0303x; 1.0303x over previous
//
#include <hip/hip_runtime.h>
#include <cstdint>
#include <cstddef>

#define B_   32
#define TIN  512
#define D_   384
#define F_   384
#define TOUT 4096
#define TPAD 514            // 512 + zero row on each side
#define MTOT (B_ * TIN)     // 16384

typedef __bf16 bf16x8 __attribute__((ext_vector_type(8)));
typedef float  f32x4  __attribute__((ext_vector_type(4)));

__device__ __forceinline__ unsigned short f2bf(float f) {
  unsigned int u = __float_as_uint(f);
  u += 0x7fff + ((u >> 16) & 1);   // round-to-nearest-even
  return (unsigned short)(u >> 16);
}

__device__ __forceinline__ void load16_to_lds(const void* g, void* l) {
  __builtin_amdgcn_global_load_lds(
      (const __attribute__((address_space(1))) unsigned int*)g,
      (__attribute__((address_space(3))) unsigned int*)l, 16, 0, 0);
}

// ---------------------------------------------------------------- prep (fused)
// block ranges:
//   [0,32)            : per-batch cumsum + searchsorted -> idxv
//   [32, 32+3456)     : weight transpose Wt[k][f][d] = bf16(w[f][d][k])
//   [3488, 3488+96)   : zero the two pad rows of h1p per batch
//   [3584, 3584+6168) : pad+convert x -> xp[b][tp][d] (bf16, zero boundary rows)
#define PB_CUM 32
#define PB_W   3456
#define PB_Z   96
#define PB_PX  6168
#define PB_TOT (PB_CUM + PB_W + PB_Z + PB_PX)

__global__ __launch_bounds__(256) void prep_all(
    const float* __restrict__ w1, const float* __restrict__ w2,
    unsigned short* __restrict__ Wt1, unsigned short* __restrict__ Wt2,
    unsigned short* __restrict__ h1p,
    const int* __restrict__ target, int* __restrict__ idxv,
    const float4* __restrict__ x4, unsigned short* __restrict__ xp) {
  int bx = blockIdx.x;
  int tid = threadIdx.x;

  if (bx < PB_CUM) {
    // ---- cumsum + binary search (one block per batch, 256 thr handle 512)
    __shared__ int ends[512];
    __shared__ int ps[256];
    int b = bx;
    int a0 = target[b * TIN + 2 * tid];
    int a1 = target[b * TIN + 2 * tid + 1];
    ps[tid] = a0 + a1;
    __syncthreads();
    for (int off = 1; off < 256; off <<= 1) {
      int add = (tid >= off) ? ps[tid - off] : 0;
      __syncthreads();
      ps[tid] += add;
      __syncthreads();
    }
    int incl = ps[tid];
    ends[2 * tid + 1] = incl;
    ends[2 * tid]     = incl - a1;
    __syncthreads();
    for (int p = 0; p < 16; ++p) {
      int m = p * 256 + tid;
      int lo = 0, hi = 512;              // first j with ends[j] > m
      while (lo < hi) {
        int mid = (lo + hi) >> 1;
        if (ends[mid] <= m) lo = mid + 1; else hi = mid;
      }
      idxv[b * TOUT + m] = (lo < TIN) ? lo : -1;
    }
    return;
  }
  bx -= PB_CUM;

  if (bx < PB_W) {
    int g = bx * 256 + tid;                     // < 884736
    const int WE = 3 * F_ * D_;                 // 442368
    int which = g >= WE;
    const float* w = which ? w2 : w1;
    unsigned short* o = which ? Wt2 : Wt1;
    int e = g - which * WE;
    int k = e / (F_ * D_);
    int rem = e - k * (F_ * D_);
    int f = rem / D_;
    int d = rem - f * D_;
    o[e] = f2bf(w[(f * D_ + d) * 3 + k]);
    return;
  }
  bx -= PB_W;

  if (bx < PB_Z) {
    int z = bx * 256 + tid;                     // < 24576
    int zr = z / D_;
    int c = z - zr * D_;
    int b = zr >> 1;
    int tp = (zr & 1) ? (TPAD - 1) : 0;
    h1p[((size_t)(b * TPAD + tp)) * D_ + c] = 0;
    return;
  }
  bx -= PB_Z;

  {
    int g = bx * 256 + tid;                     // 32*514*96 = 1,579,008
    int row = g / 96;
    int c4 = g - row * 96;
    int b = row / TPAD;
    int tp = row - b * TPAD;
    ushort4 o;
    if (tp == 0 || tp == TPAD - 1) {
      o.x = 0; o.y = 0; o.z = 0; o.w = 0;
    } else {
      float4 v = x4[((size_t)(b * TIN + tp - 1)) * 96 + c4];
      o.x = f2bf(v.x); o.y = f2bf(v.y); o.z = f2bf(v.z); o.w = f2bf(v.w);
    }
    *(ushort4*)(xp + (size_t)row * D_ + c4 * 4) = o;
  }
}

// ---------------------------------------------------------------- conv tile
// out[bt][f] = sum_{kw,d} Ap[b][t+kw][d] * Wt[kw][f][d] + bias[f]
// 128x128 tile, BK=32, 4 waves x (4x4) mfma_f32_16x16x32_bf16, m97 staging.
__device__ __forceinline__ void conv_tile(const unsigned short* __restrict__ Ap,
                                          const unsigned short* __restrict__ Wt,
                                          const float* __restrict__ bias,
                                          float* __restrict__ out, int cb) {
  __shared__ __align__(16) unsigned short As[128 * 32];
  __shared__ __align__(16) unsigned short Bs[128 * 32];
  const int tid  = threadIdx.x;
  const int wave = tid >> 6;
  const int lane = tid & 63;
  const int quad = lane >> 4;
  const int l15  = lane & 15;
  const int wm = (wave >> 1) * 64;
  const int wn = (wave & 1) * 64;
  const int mt = cb / 3;           // consecutive cb share the A tile (L2 reuse)
  const int nt = cb - mt * 3;
  const int m0 = mt * 128;
  const int n0 = nt * 128;
  const int b  = m0 >> 9;          // M-tiles never cross batch (512 % 128 == 0)
  const int t0 = m0 & 511;

  const int srow = tid >> 2;       // 0..63
  const int scol = (tid & 3) * 8;  // 0,8,16,24

  f32x4 acc[4][4];
  for (int i = 0; i < 4; ++i)
    for (int j = 0; j < 4; ++j)
      acc[i][j] = (f32x4){0.f, 0.f, 0.f, 0.f};

  for (int kc = 0; kc < 36; ++kc) {
    int kw = kc / 12;
    int d0 = (kc - kw * 12) * 32;
    for (int r = 0; r < 2; ++r) {
      int row = r * 64 + srow;
      const unsigned short* ga = Ap + (size_t)(b * TPAD + t0 + row + kw) * D_ + d0 + scol;
      load16_to_lds(ga, (char*)As + r * 4096 + wave * 1024);
      const unsigned short* gb = Wt + (size_t)(kw * F_ + n0 + row) * D_ + d0 + scol;
      load16_to_lds(gb, (char*)Bs + r * 4096 + wave * 1024);
    }
    __syncthreads();   // barrier drains vmcnt -> LDS tiles visible
    bf16x8 av[4], bv[4];
    for (int mi = 0; mi < 4; ++mi)
      av[mi] = *(const bf16x8*)(As + (wm + mi * 16 + l15) * 32 + quad * 8);
    for (int ni = 0; ni < 4; ++ni)
      bv[ni] = *(const bf16x8*)(Bs + (wn + ni * 16 + l15) * 32 + quad * 8);
    for (int mi = 0; mi < 4; ++mi)
      for (int ni = 0; ni < 4; ++ni)
        acc[mi][ni] = __builtin_amdgcn_mfma_f32_16x16x32_bf16(av[mi], bv[ni], acc[mi][ni], 0, 0, 0);
    __syncthreads();   // protect LDS from next iteration's staging
  }

  for (int mi = 0; mi < 4; ++mi) {
    int mrow = m0 + wm + mi * 16 + quad * 4;
    for (int ni = 0; ni < 4; ++ni) {
      int ncol = n0 + wn + ni * 16 + l15;
      float bb = bias[ncol];
      for (int r = 0; r < 4; ++r)
        out[(size_t)(mrow + r) * F_ + ncol] = acc[mi][ni][r] + bb;
    }
  }
}

// ---------------------------------------------------------------- conv+gather
// 768 blocks: even -> conv tile (384), odd -> gather slice (384 of 768 total).
// Interleaving spreads MFMA blocks across all CUs; the memory-bound gather
// backfills conv's barrier/imbalance bubbles (MFMA+VMEM pipes co-schedule).
__global__ __launch_bounds__(256) void conv_gather(
    const unsigned short* __restrict__ Ap, const unsigned short* __restrict__ Wt,
    const float* __restrict__ bias, float* __restrict__ out,
    const float4* __restrict__ x4, const int* __restrict__ idxv,
    float4* __restrict__ out4, int gpart) {
  int bx = blockIdx.x;
  if ((bx & 1) == 0) {
    conv_tile(Ap, Wt, bias, out, bx >> 1);
  } else {
    int gb = gpart * 384 + (bx >> 1);           // 0..767 across the two launches
    int g = gb * 256 + (int)threadIdx.x;
    for (int it = 0; it < 64; ++it, g += 768 * 256) {   // covers 12,582,912 float4
      int fr = g / 96;
      int c = g - fr * 96;
      int id = idxv[fr];
      int b = fr >> 12;
      float4 v = {0.f, 0.f, 0.f, 0.f};
      if (id >= 0) v = x4[(size_t)(b * TIN + id) * 96 + c];
      out4[g] = v;
    }
  }
}

// ---------------------------------------------------------------- LN passes
// one wave per row (384 cols = 6 per lane)
__global__ void ln_relu(const float* __restrict__ in, const float* __restrict__ gam,
                        const float* __restrict__ bet, unsigned short* __restrict__ hp) {
  int row = blockIdx.x * 4 + (threadIdx.x >> 6);
  int lane = threadIdx.x & 63;
  const float* p = in + (size_t)row * F_;
  float v[6];
  float s = 0.f, ss = 0.f;
  for (int j = 0; j < 6; ++j) {
    v[j] = p[lane + j * 64];
    s += v[j];
    ss += v[j] * v[j];
  }
  for (int off = 32; off; off >>= 1) {
    s  += __shfl_xor(s, off);
    ss += __shfl_xor(ss, off);
  }
  float mean = s * (1.f / 384.f);
  float var  = ss * (1.f / 384.f) - mean * mean;
  float rstd = rsqrtf(var + 1e-5f);
  int b = row >> 9, t = row & 511;
  unsigned short* o = hp + ((size_t)(b * TPAD + t + 1)) * D_;
  for (int j = 0; j < 6; ++j) {
    int c = lane + j * 64;
    float y = (v[j] - mean) * rstd * gam[c] + bet[c];
    y = y > 0.f ? y : 0.f;
    o[c] = f2bf(y);
  }
}

__global__ void ln_dot(const float* __restrict__ in, const float* __restrict__ gam,
                       const float* __restrict__ bet, const float* __restrict__ lw,
                       const float* __restrict__ lb, float* __restrict__ dur) {
  int row = blockIdx.x * 4 + (threadIdx.x >> 6);
  int lane = threadIdx.x & 63;
  const float* p = in + (size_t)row * F_;
  float v[6];
  float s = 0.f, ss = 0.f;
  for (int j = 0; j < 6; ++j) {
    v[j] = p[lane + j * 64];
    s += v[j];
    ss += v[j] * v[j];
  }
  for (int off = 32; off; off >>= 1) {
    s  += __shfl_xor(s, off);
    ss += __shfl_xor(ss, off);
  }
  float mean = s * (1.f / 384.f);
  float var  = ss * (1.f / 384.f) - mean * mean;
  float rstd = rsqrtf(var + 1e-5f);
  float acc = 0.f;
  for (int j = 0; j < 6; ++j) {
    int c = lane + j * 64;
    float y = (v[j] - mean) * rstd * gam[c] + bet[c];
    y = y > 0.f ? y : 0.f;
    acc += y * lw[c];
  }
  for (int off = 32; off; off >>= 1) acc += __shfl_xor(acc, off);
  if (lane == 0) dur[row] = acc + lb[0];
}

// ---------------------------------------------------------------- launch
extern "C" void kernel_launch(void* const* d_in, const int* in_sizes, int n_in,
                              void* d_out, int out_size, void* d_ws, size_t ws_size,
                              hipStream_t stream) {
  const float* x      = (const float*)d_in[0];
  const int*   target = (const int*)d_in[1];
  const float* w1  = (const float*)d_in[3];
  const float* b1  = (const float*)d_in[4];
  const float* g1  = (const float*)d_in[5];
  const float* be1 = (const float*)d_in[6];
  const float* w2  = (const float*)d_in[7];
  const float* b2  = (const float*)d_in[8];
  const float* g2  = (const float*)d_in[9];
  const float* be2 = (const float*)d_in[10];
  const float* lw  = (const float*)d_in[11];
  const float* lb  = (const float*)d_in[12];

  float* out = (float*)d_out;
  float* dur = out + (size_t)B_ * TOUT * D_;   // outputs concatenated flat

  // workspace carve (all offsets 256B-aligned)
  char* ws = (char*)d_ws;
  unsigned short* xp  = (unsigned short*)(ws);                 // 32*514*384 bf16 = 12,632,064 B
  unsigned short* h1p = (unsigned short*)(ws + 12632064);      // same
  unsigned short* Wt1 = (unsigned short*)(ws + 25264128);      // 3*384*384 bf16 = 884,736 B
  unsigned short* Wt2 = (unsigned short*)(ws + 26148864);      // 884,736 B
  float*          gbf = (float*)(ws + 27033600);               // 16384*384 f32 = 25,165,824 B
  int*            idxv = (int*)(ws + 52199424);                // 32*4096 int = 524,288 B

  hipLaunchKernelGGL(prep_all, dim3(PB_TOT), dim3(256), 0, stream,
                     w1, w2, Wt1, Wt2, h1p, target, idxv, (const float4*)x, xp);
  hipLaunchKernelGGL(conv_gather, dim3(768), dim3(256), 0, stream,
                     xp, Wt1, b1, gbf, (const float4*)x, idxv, (float4*)out, 0);
  hipLaunchKernelGGL(ln_relu, dim3(4096), dim3(256), 0, stream, gbf, g1, be1, h1p);
  hipLaunchKernelGGL(conv_gather, dim3(768), dim3(256), 0, stream,
                     h1p, Wt2, b2, gbf, (const float4*)x, idxv, (float4*)out, 1);
  hipLaunchKernelGGL(ln_dot, dim3(4096), dim3(256), 0, stream, gbf, g2, be2, lw, lb, dur);
}